// Round 4
// baseline (397.334 us; speedup 1.0000x reference)
//
#include <hip/hip_runtime.h>
#include <hip/hip_bf16.h>

// tRNN fused: embedding -> 6 tree levels (MFMA bf16) -> cpr(MFMA) -> softmax
// R4: 2 batch rows per block (sequential, shared A-frags), LDS exactly 32KB
//     (5 blocks/CU), cpr via MFMA for both rows, z/root stash carved in LDS.
// B=8192, SIDES=2, L=64, V=10000, D=128, C=128, R=7

typedef __attribute__((ext_vector_type(8))) short bf16x8;
typedef __attribute__((ext_vector_type(4))) float f32x4;

#define VOCN (10000 * 128)
#define CPSN (128 * 256)
#define CPRN (128 * 256)

__device__ __forceinline__ uint pk2(float a, float b) {
  union { __hip_bfloat162 h2; uint u; } cv;
  cv.h2 = __float22bfloat162_rn(make_float2(a, b));
  return cv.u;
}
__device__ __forceinline__ float fast_tanh(float x) {
  float e = __builtin_amdgcn_exp2f(x * 2.88539008f);   // exp(2x)
  return 1.0f - 2.0f * __builtin_amdgcn_rcpf(e + 1.0f);
}
__device__ __forceinline__ int slotf(int r) { return r ^ ((r >> 3) & 7); }

// ---- prep: f32 -> bf16 (voc fused with bias) into d_ws ----
__global__ void prep_kernel(const float* __restrict__ voc_w, const float* __restrict__ voc_b,
                            const float* __restrict__ cps_w, const float* __restrict__ cpr_w,
                            ushort* __restrict__ ws) {
  const int i4 = (blockIdx.x * 256 + threadIdx.x) * 4;
  if (i4 >= VOCN + CPSN + CPRN) return;
  float4 v;
  if (i4 < VOCN) {
    v = *(const float4*)(voc_w + i4);
    const float4 bb = *(const float4*)(voc_b + (i4 & 127));
    v.x += bb.x; v.y += bb.y; v.z += bb.z; v.w += bb.w;
  } else if (i4 < VOCN + CPSN) {
    v = *(const float4*)(cps_w + (i4 - VOCN));
  } else {
    v = *(const float4*)(cpr_w + (i4 - VOCN - CPSN));
  }
  uint2 w; w.x = pk2(v.x, v.y); w.y = pk2(v.z, v.w);
  *(uint2*)(ws + i4) = w;
}

// LDS layout per tree (16 KB): elem k of row r at byte (k>>3)*1024 + slot(r)*16 + (k&7)*2
template<int NODES>
__device__ __forceinline__ void level_step(char* hb, const bf16x8 (&A)[2][8],
                                           const float* __restrict__ cps_b,
                                           int l15, int lh, int wv) {
  constexpr int NTOT = 2 * NODES;
  constexpr int NT = (NTOT + 15) / 16;
  constexpr int LOG = NODES == 32 ? 5 : NODES == 16 ? 4 : NODES == 8 ? 3 :
                      NODES == 4 ? 2 : NODES == 2 ? 1 : 0;
  f32x4 acc[NT][2];
  const f32x4 zero = {0.f, 0.f, 0.f, 0.f};
#pragma unroll
  for (int nt = 0; nt < NT; ++nt) { acc[nt][0] = zero; acc[nt][1] = zero; }

#pragma unroll
  for (int nt = 0; nt < NT; ++nt) {
    int node = nt * 16 + l15;
    if constexpr (NTOT < 16) node = node < NTOT ? node : NTOT - 1;
    const int tree = node >> LOG;
    const int i = node & (NODES - 1);
    const char* tb = hb + tree * 16384 + lh * 1024;
    const int s0 = slotf(2 * i) * 16;
    const int s1 = slotf(2 * i + 1) * 16;
    bf16x8 bl[4], br[4];
#pragma unroll
    for (int q = 0; q < 4; ++q) bl[q] = *(const bf16x8*)(tb + q * 4096 + s0);
#pragma unroll
    for (int q = 0; q < 4; ++q) {
      acc[nt][0] = __builtin_amdgcn_mfma_f32_16x16x32_bf16(A[0][q], bl[q], acc[nt][0], 0, 0, 0);
      acc[nt][1] = __builtin_amdgcn_mfma_f32_16x16x32_bf16(A[1][q], bl[q], acc[nt][1], 0, 0, 0);
    }
#pragma unroll
    for (int q = 0; q < 4; ++q) br[q] = *(const bf16x8*)(tb + q * 4096 + s1);
#pragma unroll
    for (int q = 0; q < 4; ++q) {
      acc[nt][0] = __builtin_amdgcn_mfma_f32_16x16x32_bf16(A[0][4 + q], br[q], acc[nt][0], 0, 0, 0);
      acc[nt][1] = __builtin_amdgcn_mfma_f32_16x16x32_bf16(A[1][4 + q], br[q], acc[nt][1], 0, 0, 0);
    }
  }
  __syncthreads();   // all reads done before overwrite

#pragma unroll
  for (int nt = 0; nt < NT; ++nt) {
    int node = nt * 16 + l15;
    bool valid = true;
    if constexpr (NTOT < 16) { valid = node < NTOT; if (!valid) node = NTOT - 1; }
    const int tree = node >> LOG;
    const int i = node & (NODES - 1);
    char* tw = hb + tree * 16384 + slotf(i) * 16;
#pragma unroll
    for (int mt = 0; mt < 2; ++mt) {
      const int d0 = wv * 32 + mt * 16 + lh * 4;
      const float4 bb = *(const float4*)(cps_b + d0);
      uint2 w;
      w.x = pk2(fast_tanh(acc[nt][mt][0] + bb.x), fast_tanh(acc[nt][mt][1] + bb.y));
      w.y = pk2(fast_tanh(acc[nt][mt][2] + bb.z), fast_tanh(acc[nt][mt][3] + bb.w));
      if (valid) *(uint2*)(tw + (d0 >> 3) * 1024 + (d0 & 7) * 2) = w;
    }
  }
  __syncthreads();
}

__device__ __forceinline__ void run_levels(char* hb, const bf16x8 (&A)[2][8],
                                           const float* __restrict__ cps_b,
                                           int l15, int lh, int wv) {
  level_step<32>(hb, A, cps_b, l15, lh, wv);
  level_step<16>(hb, A, cps_b, l15, lh, wv);
  level_step<8>(hb, A, cps_b, l15, lh, wv);
  level_step<4>(hb, A, cps_b, l15, lh, wv);
  level_step<2>(hb, A, cps_b, l15, lh, wv);
  level_step<1>(hb, A, cps_b, l15, lh, wv);
}

template<int PRE>
__device__ __forceinline__ void load_afrags(bf16x8 (&A)[2][8], const ushort* __restrict__ bfp,
                                            const float* __restrict__ fp,
                                            int l15, int lh, int wv) {
#pragma unroll
  for (int mt = 0; mt < 2; ++mt) {
    const int d = wv * 32 + mt * 16 + l15;
#pragma unroll
    for (int kt = 0; kt < 8; ++kt) {
      const int k = kt * 32 + lh * 8;
      if constexpr (PRE) {
        A[mt][kt] = *(const bf16x8*)(bfp + d * 256 + k);
      } else {
        const float* p = fp + d * 256 + k;
        float4 lo = *(const float4*)p, hi = *(const float4*)(p + 4);
        union { bf16x8 v; uint4 u; } f;
        f.u.x = pk2(lo.x, lo.y); f.u.y = pk2(lo.z, lo.w);
        f.u.z = pk2(hi.x, hi.y); f.u.w = pk2(hi.z, hi.w);
        A[mt][kt] = f.v;
      }
    }
  }
}

template<int PRE>
__device__ __forceinline__ void embed_row(char* hb, const int* __restrict__ trow,
                                          const float* __restrict__ voc_w,
                                          const float* __restrict__ voc_b,
                                          const ushort* __restrict__ voc_bf, int tid) {
  const int tree = tid >> 7, lf = (tid >> 1) & 63, half = tid & 1;
  const int tok = trow[tree * 64 + lf];
  char* tp = hb + tree * 16384 + half * 8192 + slotf(lf) * 16;
  if constexpr (PRE) {
    const ushort* vr = voc_bf + tok * 128 + half * 64;
#pragma unroll
    for (int j = 0; j < 8; ++j)
      *(uint4*)(tp + j * 1024) = *(const uint4*)(vr + j * 8);
  } else {
    const float* vw = voc_w + tok * 128 + half * 64;
    const float* vb = voc_b + half * 64;
#pragma unroll
    for (int j = 0; j < 8; ++j) {
      float4 v0 = *(const float4*)(vw + j * 8);
      float4 v1 = *(const float4*)(vw + j * 8 + 4);
      float4 q0 = *(const float4*)(vb + j * 8);
      float4 q1 = *(const float4*)(vb + j * 8 + 4);
      uint4 w;
      w.x = pk2(v0.x + q0.x, v0.y + q0.y);
      w.y = pk2(v0.z + q0.z, v0.w + q0.w);
      w.z = pk2(v1.x + q1.x, v1.y + q1.y);
      w.w = pk2(v1.z + q1.z, v1.w + q1.w);
      *(uint4*)(tp + j * 1024) = w;
    }
  }
}

template<int PRE>
__global__ __launch_bounds__(256, 5)
void trnn_kernel(const int* __restrict__ tokens,
                 const float* __restrict__ voc_w, const float* __restrict__ voc_b,
                 const float* __restrict__ cps_w, const float* __restrict__ cps_b,
                 const float* __restrict__ cpr_w, const float* __restrict__ cpr_b,
                 const float* __restrict__ sm_w, const float* __restrict__ sm_b,
                 const ushort* __restrict__ wsb, float* __restrict__ out) {
  __shared__ ushort h[16384];      // exactly 32 KB: 2 trees x (16 chunks x 64 slots x 16B)
  const int tid = threadIdx.x;
  const int lane = tid & 63, wv = tid >> 6;
  const int l15 = lane & 15, lh = lane >> 4;
  const int b0 = blockIdx.x * 2;
  char* hb = (char*)h;

  const ushort* voc_bf = wsb;
  const ushort* cps_bf = wsb + VOCN;
  const ushort* cpr_bf = wsb + VOCN + CPSN;

  bf16x8 A[2][8];
  load_afrags<PRE>(A, cps_bf, cps_w, l15, lh, wv);

  // ---- row 0 ----
  embed_row<PRE>(hb, tokens + b0 * 128, voc_w, voc_b, voc_bf, tid);
  __syncthreads();
  run_levels(hb, A, cps_b, l15, lh, wv);

  // stash row-0 roots (2 trees x 128 bf16 = 512B) into regs: thread t<128 holds 1 uint
  uint stash = 0;
  if (tid < 128) {
    const int T = tid >> 6, d2 = tid & 63;
    stash = *(const uint*)(hb + T * 16384 + ((2 * d2) >> 3) * 1024 + ((2 * d2) & 7) * 2);
  }
  __syncthreads();   // readback done before row-1 overwrites

  // ---- row 1 ----
  embed_row<PRE>(hb, tokens + (b0 + 1) * 128, voc_w, voc_b, voc_bf, tid);
  __syncthreads();
  run_levels(hb, A, cps_b, l15, lh, wv);

  // write row-0 roots to slot 2 (dead bytes); load cpr A-frags (A is dead now)
  if (tid < 128) {
    const int T = tid >> 6, d2 = tid & 63;
    *(uint*)(hb + T * 16384 + ((2 * d2) >> 3) * 1024 + 32 + ((2 * d2) & 7) * 2) = stash;
  }
  bf16x8 Acpr[2][8];
  load_afrags<PRE>(Acpr, cpr_bf, cpr_w, l15, lh, wv);
  __syncthreads();

  // ---- cpr for both rows in one MFMA round ----
  // B: node n = batch row (0: stash at slot byte 32, 1: roots at slot byte 0)
  {
    const int n = l15 < 2 ? l15 : 1;
    const int slotbyte = (n == 0) ? 32 : 0;
    bf16x8 bf[8];
#pragma unroll
    for (int kt = 0; kt < 8; ++kt) {
      const int tree = kt >> 2;
      const int dk0 = (kt & 3) * 32 + lh * 8;
      bf[kt] = *(const bf16x8*)(hb + tree * 16384 + (dk0 >> 3) * 1024 + slotbyte);
    }
    const f32x4 zero = {0.f, 0.f, 0.f, 0.f};
    f32x4 az[2] = {zero, zero};
#pragma unroll
    for (int kt = 0; kt < 8; ++kt) {
      az[0] = __builtin_amdgcn_mfma_f32_16x16x32_bf16(Acpr[0][kt], bf[kt], az[0], 0, 0, 0);
      az[1] = __builtin_amdgcn_mfma_f32_16x16x32_bf16(Acpr[1][kt], bf[kt], az[1], 0, 0, 0);
    }
    if (l15 < 2) {
#pragma unroll
      for (int mt = 0; mt < 2; ++mt) {
        const int c0 = wv * 32 + mt * 16 + lh * 4;
        const float4 bb = *(const float4*)(cpr_b + c0);
        float4 zv;
        zv.x = az[mt][0] + bb.x; zv.x = zv.x > 0.f ? zv.x : 0.01f * zv.x;
        zv.y = az[mt][1] + bb.y; zv.y = zv.y > 0.f ? zv.y : 0.01f * zv.y;
        zv.z = az[mt][2] + bb.z; zv.z = zv.z > 0.f ? zv.z : 0.01f * zv.z;
        zv.w = az[mt][3] + bb.w; zv.w = zv.w > 0.f ? zv.w : 0.01f * zv.w;
        // z for row n at carved bytes 768..799 of each chunk of tree-n's buffer
        *(float4*)(hb + n * 16384 + ((c0 >> 3) << 10) + 768 + ((c0 & 7) << 2)) = zv;
      }
    }
  }
  __syncthreads();

  // ---- softmax: wave 0 -> row 0, wave 1 -> row 1 ----
  if (wv < 2) {
    const char* zb = hb + wv * 16384;
    const int i0 = lane, i1 = 64 + lane;
    const float za = *(const float*)(zb + ((i0 >> 3) << 10) + 768 + ((i0 & 7) << 2));
    const float zc = *(const float*)(zb + ((i1 >> 3) << 10) + 768 + ((i1 & 7) << 2));
    float p[7];
#pragma unroll
    for (int j = 0; j < 7; ++j)
      p[j] = za * sm_w[j * 128 + lane] + zc * sm_w[j * 128 + 64 + lane];
#pragma unroll
    for (int j = 0; j < 7; ++j) {
      float v = p[j];
#pragma unroll
      for (int off = 32; off >= 1; off >>= 1) v += __shfl_xor(v, off, 64);
      p[j] = v + sm_b[j];
    }
    float mx = p[0];
#pragma unroll
    for (int j = 1; j < 7; ++j) mx = fmaxf(mx, p[j]);
    float e[7], s = 0.f;
#pragma unroll
    for (int j = 0; j < 7; ++j) { e[j] = __expf(p[j] - mx); s += e[j]; }
    const float inv = 1.f / s;
    if (lane == 0) {
#pragma unroll
      for (int j = 0; j < 7; ++j) out[(b0 + wv) * 7 + j] = e[j] * inv;
    }
  }
}

extern "C" void kernel_launch(void* const* d_in, const int* in_sizes, int n_in,
                              void* d_out, int out_size, void* d_ws, size_t ws_size,
                              hipStream_t stream) {
  const int*   tokens = (const int*)  d_in[0];
  const float* voc_w  = (const float*)d_in[1];
  const float* voc_b  = (const float*)d_in[2];
  const float* cps_w  = (const float*)d_in[3];
  const float* cps_b  = (const float*)d_in[4];
  const float* cpr_w  = (const float*)d_in[5];
  const float* cpr_b  = (const float*)d_in[6];
  const float* sm_w   = (const float*)d_in[7];
  const float* sm_b   = (const float*)d_in[8];
  float* out = (float*)d_out;

  const int B = in_sizes[0] / 128;                     // 8192
  const size_t need = (size_t)(VOCN + CPSN + CPRN) * sizeof(ushort);

  if (ws_size >= need) {
    ushort* ws = (ushort*)d_ws;
    const int tot4 = (VOCN + CPSN + CPRN) / 4;
    prep_kernel<<<(tot4 + 255) / 256, 256, 0, stream>>>(voc_w, voc_b, cps_w, cpr_w, ws);
    trnn_kernel<1><<<B / 2, 256, 0, stream>>>(tokens, voc_w, voc_b, cps_w, cps_b,
                                              cpr_w, cpr_b, sm_w, sm_b, ws, out);
  } else {
    trnn_kernel<0><<<B / 2, 256, 0, stream>>>(tokens, voc_w, voc_b, cps_w, cps_b,
                                              cpr_w, cpr_b, sm_w, sm_b,
                                              (const ushort*)d_ws, out);
  }
}